// Round 8
// baseline (2216.737 us; speedup 1.0000x reference)
//
#include <hip/hip_runtime.h>
#include <hip/hip_bf16.h>
#include <math.h>

#define B_    4
#define C_    192
#define NPT   3136          // H*W points per batch
#define CO_   384           // Cout
#define KNN   9
#define LDEPTH 10           // per-thread screening list depth
#define CAND  80            // 8 col-threads * LDEPTH candidates per row
#define NROWS (B_*NPT)      // 12544 total points

// ---------------------------------------------------------------------------
// K1: per-point f64 norm stats from fp32 x.
// ---------------------------------------------------------------------------
__global__ __launch_bounds__(256) void k_norm(
    const float* __restrict__ x,
    float* __restrict__ invn32, double* __restrict__ invn64,
    double* __restrict__ sqd)
{
    int p = blockIdx.x * 256 + threadIdx.x;
    if (p >= NROWS) return;
    int b = p / NPT, n = p % NPT;
    const float* xb = x + (size_t)b * C_ * NPT + n;
    double S = 0.0;
    for (int c = 0; c < C_; ++c) {
        double v = (double)xb[(size_t)c * NPT];
        S = fma(v, v, S);
    }
    double nrm = sqrt(S);
    if (nrm < 1e-12) nrm = 1e-12;
    double iv = 1.0 / nrm;
    invn64[p] = iv;
    invn32[p] = (float)iv;
    sqd[p] = iv * iv * S;
}

// ---------------------------------------------------------------------------
// K2: fp32 screening (normalized dots) fused with per-thread top-10 lists.
//     Union of 8 per-thread top-10 lists provably contains the true top-9
//     (each thread owns disjoint j columns; LDEPTH=10 >= 9).
// ---------------------------------------------------------------------------
#define TM 32
#define TN 64
#define TC 32
__global__ __launch_bounds__(256) void k_screen(
    const float* __restrict__ x, const float* __restrict__ invn32,
    unsigned short* __restrict__ cand)
{
    __shared__ float Xi[TC][TM];
    __shared__ float Xj[TC][TN];
    __shared__ float sIi[TM];
    __shared__ float sIj[TN];
    int blk = blockIdx.x;
    int b   = blk / (NPT / TM);
    int i0  = (blk % (NPT / TM)) * TM;
    int tid = threadIdx.x;
    int ty  = tid >> 3;
    int tx  = tid & 7;
    const float* xb = x + (size_t)b * C_ * NPT;

    if (tid < TM) sIi[tid] = invn32[(size_t)b * NPT + i0 + tid];

    float bdot[LDEPTH];
    int   bidx[LDEPTH];
#pragma unroll
    for (int q = 0; q < LDEPTH; ++q) { bdot[q] = -1e30f; bidx[q] = 0; }

    for (int jt = 0; jt < NPT / TN; ++jt) {
        int j0 = jt * TN;
        if (tid < TN) sIj[tid] = invn32[(size_t)b * NPT + j0 + tid];
        __syncthreads();
        float acc[8];
#pragma unroll
        for (int k = 0; k < 8; ++k) acc[k] = 0.f;

        for (int ct = 0; ct < C_ / TC; ++ct) {
            int c0 = ct * TC;
#pragma unroll
            for (int e = 0; e < 4; ++e) {       // Xi: 32x32
                int id = tid + e * 256;
                int cc = id >> 5, r = id & 31;
                Xi[cc][r] = xb[(size_t)(c0 + cc) * NPT + i0 + r] * sIi[r];
            }
#pragma unroll
            for (int e = 0; e < 8; ++e) {       // Xj: 32x64
                int id = tid + e * 256;
                int cc = id >> 6, jj = id & 63;
                Xj[cc][jj] = xb[(size_t)(c0 + cc) * NPT + j0 + jj] * sIj[jj];
            }
            __syncthreads();
#pragma unroll
            for (int cc = 0; cc < TC; ++cc) {
                float a = Xi[cc][ty];
                const float4* xjv = (const float4*)&Xj[cc][tx * 8];
                float4 v0 = xjv[0], v1 = xjv[1];
                acc[0] = fmaf(a, v0.x, acc[0]);
                acc[1] = fmaf(a, v0.y, acc[1]);
                acc[2] = fmaf(a, v0.z, acc[2]);
                acc[3] = fmaf(a, v0.w, acc[3]);
                acc[4] = fmaf(a, v1.x, acc[4]);
                acc[5] = fmaf(a, v1.y, acc[5]);
                acc[6] = fmaf(a, v1.z, acc[6]);
                acc[7] = fmaf(a, v1.w, acc[7]);
            }
            __syncthreads();
        }
#pragma unroll
        for (int k = 0; k < 8; ++k) {
            float d = acc[k];
            if (d > bdot[LDEPTH - 1]) {
                bdot[LDEPTH - 1] = d;
                bidx[LDEPTH - 1] = j0 + tx * 8 + k;
#pragma unroll
                for (int q = LDEPTH - 1; q > 0; --q) {
                    if (bdot[q] > bdot[q - 1]) {
                        float td = bdot[q]; bdot[q] = bdot[q - 1]; bdot[q - 1] = td;
                        int   tj = bidx[q]; bidx[q] = bidx[q - 1]; bidx[q - 1] = tj;
                    }
                }
            }
        }
    }
    unsigned short* cp = cand + ((size_t)b * NPT + i0 + ty) * CAND + tx * LDEPTH;
#pragma unroll
    for (int q = 0; q < LDEPTH; ++q) cp[q] = (unsigned short)bidx[q];
}

// ---------------------------------------------------------------------------
// K3: f64 refine of 80 candidates/row; exact top-9 (dist asc, idx asc);
//     writes edge plane0 (nn idx) and plane1 (center) directly as fp32.
// ---------------------------------------------------------------------------
__global__ __launch_bounds__(256) void k_refine(
    const float* __restrict__ x, const double* __restrict__ invn64,
    const double* __restrict__ sqd, const unsigned short* __restrict__ cand,
    float* __restrict__ e0, float* __restrict__ e1)
{
    __shared__ double dbuf[4][CAND];
    __shared__ int    icand[4][CAND];
    int wave = threadIdx.x >> 6;
    int lane = threadIdx.x & 63;
    int row  = blockIdx.x * 4 + wave;
    int b    = row / NPT, i = row % NPT;

    const unsigned short* cp = cand + (size_t)row * CAND;
    icand[wave][lane] = (int)cp[lane];
    if (lane < CAND - 64) icand[wave][64 + lane] = (int)cp[64 + lane];
    __syncthreads();

    int sub = lane & 7, cg = lane >> 3;
    const float* xb = x + (size_t)b * C_ * NPT;
    double xif[24];
#pragma unroll
    for (int q = 0; q < 24; ++q)
        xif[q] = (double)xb[(size_t)(sub * 24 + q) * NPT + i];
    double ivi = invn64[row], sqi = sqd[row];

    for (int cc = 0; cc < CAND / 8; ++cc) {
        int cidx = cc * 8 + cg;
        int j = icand[wave][cidx];
        double dot = 0.0;
#pragma unroll
        for (int q = 0; q < 24; ++q)
            dot = fma(xif[q], (double)xb[(size_t)(sub * 24 + q) * NPT + j], dot);
        dot += __shfl_xor(dot, 1);
        dot += __shfl_xor(dot, 2);
        dot += __shfl_xor(dot, 4);
        if (sub == 0)
            dbuf[wave][cidx] = sqi + sqd[(size_t)b * NPT + j]
                             - 2.0 * (ivi * invn64[(size_t)b * NPT + j] * dot);
    }
    __syncthreads();

    if (lane == 0) {
        float* p0 = e0 + (size_t)row * KNN;
        float* p1 = e1 + (size_t)row * KNN;
        for (int q = 0; q < KNN; ++q) {
            double best = 1e300; int bj = 0x7fffffff; int bc = 0;
            for (int t = 0; t < CAND; ++t) {
                double d = dbuf[wave][t]; int j = icand[wave][t];
                if (d < best || (d == best && j < bj)) { best = d; bj = j; bc = t; }
            }
            dbuf[wave][bc] = 1e301;
            p0[q] = (float)bj;
            p1[q] = (float)i;
        }
    }
}

// ---------------------------------------------------------------------------
// K4: fully-fused conv+BN+GELU+max. Block = (batch, 64 points, 64 outs).
//     z_A = (W1-W2) x_i (one GEMM), then per k: gathered GEMM W2 x_{j_k},
//     online max of gelu. Neighbor indices read from edge plane0 (fp32).
// ---------------------------------------------------------------------------
__global__ __launch_bounds__(256) void k_fused(
    const float* __restrict__ x, const float* __restrict__ cw,
    const float* __restrict__ e0,
    const float* __restrict__ cb, const float* __restrict__ gam,
    const float* __restrict__ bet, float* __restrict__ out)
{
    __shared__ float Xi[16][72];
    __shared__ float Xg[16][72];
    __shared__ float Wd[16][72];
    __shared__ float W2t[16][72];
    __shared__ unsigned short jidx[64 * KNN];

    int blk = blockIdx.x;
    int b  = blk / 294;
    int r  = blk % 294;
    int nt = r % 49, ot = r / 49;
    int n0 = nt * 64, o0 = ot * 64;
    int tid = threadIdx.x;
    int tx = tid & 15, ty = tid >> 4;
    const float* xb = x + (size_t)b * C_ * NPT;

    for (int e = tid; e < 64 * KNN; e += 256)
        jidx[e] = (unsigned short)(int)
            e0[((size_t)b * NPT + n0 + e / KNN) * KNN + e % KNN];
    __syncthreads();

    float zA[4][4];
#pragma unroll
    for (int u = 0; u < 4; ++u)
#pragma unroll
        for (int v = 0; v < 4; ++v) zA[u][v] = 0.f;

    for (int ct = 0; ct < C_ / 16; ++ct) {
        int c0 = ct * 16;
#pragma unroll
        for (int e = 0; e < 4; ++e) {
            int id = tid + e * 256;
            int cc = id >> 6, nl = id & 63;
            Xi[cc][nl] = xb[(size_t)(c0 + cc) * NPT + n0 + nl];
        }
#pragma unroll
        for (int e = 0; e < 4; ++e) {
            int id = tid + e * 256;
            int cc = id & 15, oo = id >> 4;
            int o = o0 + oo;
            Wd[cc][oo] = cw[(size_t)o * 384 + c0 + cc]
                       - cw[(size_t)o * 384 + C_ + c0 + cc];
        }
        __syncthreads();
#pragma unroll
        for (int cc = 0; cc < 16; ++cc) {
            float4 av = *(const float4*)&Xi[cc][ty * 4];
            float4 bv = *(const float4*)&Wd[cc][tx * 4];
            float a_[4] = {av.x, av.y, av.z, av.w};
            float b_[4] = {bv.x, bv.y, bv.z, bv.w};
#pragma unroll
            for (int u = 0; u < 4; ++u)
#pragma unroll
                for (int v = 0; v < 4; ++v)
                    zA[u][v] = fmaf(a_[u], b_[v], zA[u][v]);
        }
        __syncthreads();
    }

    const float inv_s = 0.9999950000374997f;  // 1/sqrt(1+1e-5)
    float gs[4], bts[4], cbs[4];
#pragma unroll
    for (int v = 0; v < 4; ++v) {
        int o = o0 + tx * 4 + v;
        gs[v]  = gam[o] * inv_s;
        bts[v] = bet[o];
        cbs[v] = cb[o];
    }

    float best[4][4];
#pragma unroll
    for (int u = 0; u < 4; ++u)
#pragma unroll
        for (int v = 0; v < 4; ++v) best[u][v] = -1e30f;

    for (int k = 0; k < KNN; ++k) {
        float zB[4][4];
#pragma unroll
        for (int u = 0; u < 4; ++u)
#pragma unroll
            for (int v = 0; v < 4; ++v) zB[u][v] = 0.f;

        for (int ct = 0; ct < C_ / 16; ++ct) {
            int c0 = ct * 16;
#pragma unroll
            for (int e = 0; e < 4; ++e) {
                int id = tid + e * 256;
                int cc = id >> 6, nl = id & 63;
                int j = (int)jidx[nl * KNN + k];
                Xg[cc][nl] = xb[(size_t)(c0 + cc) * NPT + j];
            }
#pragma unroll
            for (int e = 0; e < 4; ++e) {
                int id = tid + e * 256;
                int cc = id & 15, oo = id >> 4;
                W2t[cc][oo] = cw[(size_t)(o0 + oo) * 384 + C_ + c0 + cc];
            }
            __syncthreads();
#pragma unroll
            for (int cc = 0; cc < 16; ++cc) {
                float4 av = *(const float4*)&Xg[cc][ty * 4];
                float4 bv = *(const float4*)&W2t[cc][tx * 4];
                float a_[4] = {av.x, av.y, av.z, av.w};
                float b_[4] = {bv.x, bv.y, bv.z, bv.w};
#pragma unroll
                for (int u = 0; u < 4; ++u)
#pragma unroll
                    for (int v = 0; v < 4; ++v)
                        zB[u][v] = fmaf(a_[u], b_[v], zB[u][v]);
            }
            __syncthreads();
        }
#pragma unroll
        for (int u = 0; u < 4; ++u)
#pragma unroll
            for (int v = 0; v < 4; ++v) {
                float z = zA[u][v] + zB[u][v] + cbs[v];
                float y = fmaf(z, gs[v], bts[v]);
                float ge = 0.5f * y * (1.0f + erff(y * 0.70710678118654752f));
                best[u][v] = fmaxf(best[u][v], ge);
            }
    }

#pragma unroll
    for (int v = 0; v < 4; ++v) {
        int o = o0 + tx * 4 + v;
        float4 pk;
        pk.x = best[0][v]; pk.y = best[1][v];
        pk.z = best[2][v]; pk.w = best[3][v];
        *(float4*)(out + ((size_t)(b * CO_ + o)) * NPT + n0 + ty * 4) = pk;
    }
}

// ---------------------------------------------------------------------------
extern "C" void kernel_launch(void* const* d_in, const int* in_sizes, int n_in,
                              void* d_out, int out_size, void* d_ws, size_t ws_size,
                              hipStream_t stream)
{
    const float* x   = (const float*)d_in[0];
    const float* cw  = (const float*)d_in[1];
    const float* cb  = (const float*)d_in[2];
    const float* gam = (const float*)d_in[3];
    const float* bet = (const float*)d_in[4];

    // d_out: FLOAT32. out0 = floats [0, 4,816,896); edge plane0 (nn idx) =
    // [4,816,896, 4,929,792); plane1 (center) = [4,929,792, 5,042,688).
    // Phase-1 scratch sits in out0's head (bytes 0..2,257,920), dead before
    // k_fused overwrites all of out0. No d_ws use (ws_size may be ~0).
    float* ou   = (float*)d_out;
    float* out0 = ou;
    double* invn64 = (double*)d_out;                       // 100,352 B @0
    double* sqd    = (double*)((char*)d_out + 100352);     // 100,352 B
    float*  invn32 = (float*)((char*)d_out + 200704);      //  50,176 B
    unsigned short* cand =
        (unsigned short*)((char*)d_out + 250880);          // 2,007,040 B
    float* e0 = ou + 4816896;
    float* e1 = ou + 4929792;

    k_norm  <<<NROWS / 256, 256, 0, stream>>>(x, invn32, invn64, sqd);
    k_screen<<<B_ * (NPT / TM), 256, 0, stream>>>(x, invn32, cand);
    k_refine<<<NROWS / 4, 256, 0, stream>>>(x, invn64, sqd, cand, e0, e1);
    k_fused <<<B_ * (NPT / 64) * (CO_ / 64), 256, 0, stream>>>(
        x, cw, e0, cb, gam, bet, out0);
}

// Round 9
// 2123.399 us; speedup vs baseline: 1.0440x; 1.0440x over previous
//
#include <hip/hip_runtime.h>
#include <hip/hip_bf16.h>
#include <math.h>

#define B_    4
#define C_    192
#define NPT   3136          // H*W points per batch
#define CO_   384           // Cout
#define KNN   9
#define LDEPTH 10           // per-thread screening list depth
#define CAND  80            // 8 col-threads * LDEPTH candidates per row
#define NROWS (B_*NPT)      // 12544 total points

__device__ __forceinline__ float u2f(unsigned short u) {
    unsigned int t = ((unsigned int)u) << 16;
    float f; __builtin_memcpy(&f, &t, 4); return f;
}
__device__ __forceinline__ unsigned short f2u(float f) {
    __hip_bfloat16 h = __float2bfloat16(f);
    unsigned short u; __builtin_memcpy(&u, &h, 2); return u;
}

// ---------------------------------------------------------------------------
// K1: per-point f64 norm stats from fp32 x.
// ---------------------------------------------------------------------------
__global__ __launch_bounds__(256) void k_norm(
    const float* __restrict__ x,
    float* __restrict__ invn32, double* __restrict__ invn64,
    double* __restrict__ sqd)
{
    int p = blockIdx.x * 256 + threadIdx.x;
    if (p >= NROWS) return;
    int b = p / NPT, n = p % NPT;
    const float* xb = x + (size_t)b * C_ * NPT + n;
    double S = 0.0;
    for (int c = 0; c < C_; ++c) {
        double v = (double)xb[(size_t)c * NPT];
        S = fma(v, v, S);
    }
    double nrm = sqrt(S);
    if (nrm < 1e-12) nrm = 1e-12;
    double iv = 1.0 / nrm;
    invn64[p] = iv;
    invn32[p] = (float)iv;
    sqd[p] = iv * iv * S;
}

// ---------------------------------------------------------------------------
// K2 v2: fp32 screening. 128 thr/block; thread owns 2 rows x 8 cols.
//   - XiL: full-K (192x32) raw x tile staged ONCE (no per-jt restage).
//   - invn_j factored out of the K-loop: rank by acc*invn_j (invn_i > 0
//     is constant per row -> same per-row ordering as full normalization).
//   Union of 8 per-thread top-10 lists contains the true top-9 per row.
// ---------------------------------------------------------------------------
__global__ __launch_bounds__(128) void k_screen2(
    const float* __restrict__ x, const float* __restrict__ invn32,
    unsigned short* __restrict__ cand)
{
    __shared__ float XiL[C_][32];     // 24,576 B raw x rows-block, full K
    __shared__ float Xj[32][64];      //  8,192 B raw x cols-tile, per ct
    __shared__ float sJ[64];
    int blk = blockIdx.x;
    int b  = blk / 98;
    int i0 = (blk % 98) * 32;
    int tid = threadIdx.x;
    int ty = tid >> 3;                // 0..15 -> rows 2ty, 2ty+1
    int tx = tid & 7;                 // cols tx*8..tx*8+7 of each j-tile
    const float* xb = x + (size_t)b * C_ * NPT;

    // stage XiL: 6144 floats = 1536 float4 / 128 thr = 12 iters
#pragma unroll
    for (int e = 0; e < 12; ++e) {
        int q = tid + e * 128;
        int cc = q >> 3, r4 = (q & 7) * 4;
        *(float4*)&XiL[cc][r4] = *(const float4*)&xb[(size_t)cc * NPT + i0 + r4];
    }

    float bd[2][LDEPTH];
    int   bi[2][LDEPTH];
#pragma unroll
    for (int r = 0; r < 2; ++r)
#pragma unroll
        for (int q = 0; q < LDEPTH; ++q) { bd[r][q] = -1e30f; bi[r][q] = 0; }

    for (int jt = 0; jt < NPT / 64; ++jt) {
        int j0 = jt * 64;
        float a0[8], a1[8];
#pragma unroll
        for (int k = 0; k < 8; ++k) { a0[k] = 0.f; a1[k] = 0.f; }
        float sjv[8];

        for (int ct = 0; ct < 6; ++ct) {
            int c0 = ct * 32;
            // stage Xj: 2048 floats = 512 f4 / 128 = 4 iters
#pragma unroll
            for (int e = 0; e < 4; ++e) {
                int q = tid + e * 128;
                int cc = q >> 4, j4 = (q & 15) * 4;
                *(float4*)&Xj[cc][j4] =
                    *(const float4*)&xb[(size_t)(c0 + cc) * NPT + j0 + j4];
            }
            if (ct == 0 && tid < 64) sJ[tid] = invn32[(size_t)b * NPT + j0 + tid];
            __syncthreads();
            if (ct == 0) {
#pragma unroll
                for (int k = 0; k < 8; ++k) sjv[k] = sJ[tx * 8 + k];
            }
#pragma unroll
            for (int cc = 0; cc < 32; ++cc) {
                float2 xi = *(const float2*)&XiL[c0 + cc][ty * 2];
                const float4* xjv = (const float4*)&Xj[cc][tx * 8];
                float4 v0 = xjv[0], v1 = xjv[1];
                a0[0] = fmaf(xi.x, v0.x, a0[0]); a1[0] = fmaf(xi.y, v0.x, a1[0]);
                a0[1] = fmaf(xi.x, v0.y, a0[1]); a1[1] = fmaf(xi.y, v0.y, a1[1]);
                a0[2] = fmaf(xi.x, v0.z, a0[2]); a1[2] = fmaf(xi.y, v0.z, a1[2]);
                a0[3] = fmaf(xi.x, v0.w, a0[3]); a1[3] = fmaf(xi.y, v0.w, a1[3]);
                a0[4] = fmaf(xi.x, v1.x, a0[4]); a1[4] = fmaf(xi.y, v1.x, a1[4]);
                a0[5] = fmaf(xi.x, v1.y, a0[5]); a1[5] = fmaf(xi.y, v1.y, a1[5]);
                a0[6] = fmaf(xi.x, v1.z, a0[6]); a1[6] = fmaf(xi.y, v1.z, a1[6]);
                a0[7] = fmaf(xi.x, v1.w, a0[7]); a1[7] = fmaf(xi.y, v1.w, a1[7]);
            }
            __syncthreads();
        }
        // insert candidates (d = acc * invn_j; invn_i factor is row-constant)
#pragma unroll
        for (int k = 0; k < 8; ++k) {
            float d0 = a0[k] * sjv[k];
            int   jj = j0 + tx * 8 + k;
            if (d0 > bd[0][LDEPTH - 1]) {
                bd[0][LDEPTH - 1] = d0; bi[0][LDEPTH - 1] = jj;
#pragma unroll
                for (int q = LDEPTH - 1; q > 0; --q)
                    if (bd[0][q] > bd[0][q - 1]) {
                        float td = bd[0][q]; bd[0][q] = bd[0][q-1]; bd[0][q-1] = td;
                        int   tj = bi[0][q]; bi[0][q] = bi[0][q-1]; bi[0][q-1] = tj;
                    }
            }
            float d1 = a1[k] * sjv[k];
            if (d1 > bd[1][LDEPTH - 1]) {
                bd[1][LDEPTH - 1] = d1; bi[1][LDEPTH - 1] = jj;
#pragma unroll
                for (int q = LDEPTH - 1; q > 0; --q)
                    if (bd[1][q] > bd[1][q - 1]) {
                        float td = bd[1][q]; bd[1][q] = bd[1][q-1]; bd[1][q-1] = td;
                        int   tj = bi[1][q]; bi[1][q] = bi[1][q-1]; bi[1][q-1] = tj;
                    }
            }
        }
    }
#pragma unroll
    for (int r = 0; r < 2; ++r) {
        unsigned short* cp =
            cand + ((size_t)b * NPT + i0 + 2 * ty + r) * CAND + tx * LDEPTH;
#pragma unroll
        for (int q = 0; q < LDEPTH; ++q) cp[q] = (unsigned short)bi[r][q];
    }
}

// ---------------------------------------------------------------------------
// K3: f64 refine of 80 candidates/row; exact top-9 (dist asc, idx asc);
//     writes edge plane0 (nn idx) and plane1 (center) as fp32.
// ---------------------------------------------------------------------------
__global__ __launch_bounds__(256) void k_refine(
    const float* __restrict__ x, const double* __restrict__ invn64,
    const double* __restrict__ sqd, const unsigned short* __restrict__ cand,
    float* __restrict__ e0, float* __restrict__ e1)
{
    __shared__ double dbuf[4][CAND];
    __shared__ int    icand[4][CAND];
    int wave = threadIdx.x >> 6;
    int lane = threadIdx.x & 63;
    int row  = blockIdx.x * 4 + wave;
    int b    = row / NPT, i = row % NPT;

    const unsigned short* cp = cand + (size_t)row * CAND;
    icand[wave][lane] = (int)cp[lane];
    if (lane < CAND - 64) icand[wave][64 + lane] = (int)cp[64 + lane];
    __syncthreads();

    int sub = lane & 7, cg = lane >> 3;
    const float* xb = x + (size_t)b * C_ * NPT;
    double xif[24];
#pragma unroll
    for (int q = 0; q < 24; ++q)
        xif[q] = (double)xb[(size_t)(sub * 24 + q) * NPT + i];
    double ivi = invn64[row], sqi = sqd[row];

    for (int cc = 0; cc < CAND / 8; ++cc) {
        int cidx = cc * 8 + cg;
        int j = icand[wave][cidx];
        double dot = 0.0;
#pragma unroll
        for (int q = 0; q < 24; ++q)
            dot = fma(xif[q], (double)xb[(size_t)(sub * 24 + q) * NPT + j], dot);
        dot += __shfl_xor(dot, 1);
        dot += __shfl_xor(dot, 2);
        dot += __shfl_xor(dot, 4);
        if (sub == 0)
            dbuf[wave][cidx] = sqi + sqd[(size_t)b * NPT + j]
                             - 2.0 * (ivi * invn64[(size_t)b * NPT + j] * dot);
    }
    __syncthreads();

    if (lane == 0) {
        float* p0 = e0 + (size_t)row * KNN;
        float* p1 = e1 + (size_t)row * KNN;
        for (int q = 0; q < KNN; ++q) {
            double best = 1e300; int bj = 0x7fffffff; int bc = 0;
            for (int t = 0; t < CAND; ++t) {
                double d = dbuf[wave][t]; int j = icand[wave][t];
                if (d < best || (d == best && j < bj)) { best = d; bj = j; bc = t; }
            }
            dbuf[wave][bc] = 1e301;
            p0[q] = (float)bj;
            p1[q] = (float)i;
        }
    }
}

// ---------------------------------------------------------------------------
// K4: B = W2 * x for one batch, cols [bcol0, bcol0 + gridDim/49*64).
//     Bq row-major [n][ldB]; fp32 or bf16 per storeBf16.
// ---------------------------------------------------------------------------
__global__ __launch_bounds__(256) void k_gemmB(
    const float* __restrict__ x, const float* __restrict__ cw,
    void* __restrict__ Bq, int b, int bcol0, int ldB, int storeBf16)
{
    __shared__ float Xt[16][68];
    __shared__ float Wt[16][68];
    int bm = blockIdx.x % 49;
    int bo = blockIdx.x / 49;
    int m0 = bm * 64;
    int tid = threadIdx.x;
    int tx = tid & 15, ty = tid >> 4;
    const float* xb = x + (size_t)b * C_ * NPT;
    float acc[4][4];
#pragma unroll
    for (int u = 0; u < 4; ++u)
#pragma unroll
        for (int v = 0; v < 4; ++v) acc[u][v] = 0.f;

    for (int ct = 0; ct < 12; ++ct) {
        int c0 = ct * 16;
        {
            int cc = tid >> 4, n4 = (tid & 15) * 4;
            *(float4*)&Xt[cc][n4] =
                *(const float4*)&xb[(size_t)(c0 + cc) * NPT + m0 + n4];
        }
        {
            int oo = tid >> 2, c4 = (tid & 3) * 4;
            int o = bcol0 + bo * 64 + oo;
            float4 w = *(const float4*)&cw[(size_t)o * 384 + C_ + c0 + c4];
            Wt[c4 + 0][oo] = w.x; Wt[c4 + 1][oo] = w.y;
            Wt[c4 + 2][oo] = w.z; Wt[c4 + 3][oo] = w.w;
        }
        __syncthreads();
#pragma unroll
        for (int cc = 0; cc < 16; ++cc) {
            float4 av = *(const float4*)&Xt[cc][ty * 4];
            float4 bv = *(const float4*)&Wt[cc][tx * 4];
            float a_[4] = {av.x, av.y, av.z, av.w};
            float b_[4] = {bv.x, bv.y, bv.z, bv.w};
#pragma unroll
            for (int u = 0; u < 4; ++u)
#pragma unroll
                for (int v = 0; v < 4; ++v)
                    acc[u][v] = fmaf(a_[u], b_[v], acc[u][v]);
        }
        __syncthreads();
    }
    if (!storeBf16) {
        float* Bf = (float*)Bq;
#pragma unroll
        for (int u = 0; u < 4; ++u) {
            float4 pk = {acc[u][0], acc[u][1], acc[u][2], acc[u][3]};
            *(float4*)&Bf[(size_t)(m0 + ty * 4 + u) * ldB + bo * 64 + tx * 4] = pk;
        }
    } else {
        unsigned short* Bh = (unsigned short*)Bq;
#pragma unroll
        for (int u = 0; u < 4; ++u) {
            ushort4 pk;
            pk.x = f2u(acc[u][0]); pk.y = f2u(acc[u][1]);
            pk.z = f2u(acc[u][2]); pk.w = f2u(acc[u][3]);
            *(ushort4*)&Bh[(size_t)(m0 + ty * 4 + u) * ldB + bo * 64 + tx * 4] = pk;
        }
    }
}

// ---------------------------------------------------------------------------
// K5: epilogue. zA = (W1-W2) x_i (on-the-fly GEMM); per k gather B_j row;
//     z = zA + B + cb; BN; gelu; online max over 9; store fp32.
// ---------------------------------------------------------------------------
__global__ __launch_bounds__(256) void k_outA(
    const float* __restrict__ x, const float* __restrict__ cw,
    const float* __restrict__ e0, const float* __restrict__ cb,
    const float* __restrict__ gam, const float* __restrict__ bet,
    float* __restrict__ out, const void* __restrict__ Bq,
    int b, int o0base, int bcol0, int ldB, int readBf16)
{
    __shared__ float Xi[16][68];
    __shared__ float Wd[16][68];
    __shared__ int jidx[64 * KNN];
    int r  = blockIdx.x;
    int nt = r % 49, ot = r / 49;
    int n0 = nt * 64, o0 = o0base + ot * 64;
    int tid = threadIdx.x;
    int tx = tid & 15, ty = tid >> 4;
    const float* xb = x + (size_t)b * C_ * NPT;

    for (int e = tid; e < 64 * KNN; e += 256)
        jidx[e] = (int)e0[((size_t)b * NPT + n0 + e / KNN) * KNN + e % KNN];

    float zA[4][4];
#pragma unroll
    for (int u = 0; u < 4; ++u)
#pragma unroll
        for (int v = 0; v < 4; ++v) zA[u][v] = 0.f;

    for (int ct = 0; ct < 12; ++ct) {
        int c0 = ct * 16;
        {
            int cc = tid >> 4, n4 = (tid & 15) * 4;
            *(float4*)&Xi[cc][n4] =
                *(const float4*)&xb[(size_t)(c0 + cc) * NPT + n0 + n4];
        }
        {
            int oo = tid >> 2, c4 = (tid & 3) * 4;
            int o = o0 + oo;
            float4 w1 = *(const float4*)&cw[(size_t)o * 384 + c0 + c4];
            float4 w2 = *(const float4*)&cw[(size_t)o * 384 + C_ + c0 + c4];
            Wd[c4 + 0][oo] = w1.x - w2.x; Wd[c4 + 1][oo] = w1.y - w2.y;
            Wd[c4 + 2][oo] = w1.z - w2.z; Wd[c4 + 3][oo] = w1.w - w2.w;
        }
        __syncthreads();
#pragma unroll
        for (int cc = 0; cc < 16; ++cc) {
            float4 av = *(const float4*)&Xi[cc][ty * 4];
            float4 bv = *(const float4*)&Wd[cc][tx * 4];
            float a_[4] = {av.x, av.y, av.z, av.w};
            float b_[4] = {bv.x, bv.y, bv.z, bv.w};
#pragma unroll
            for (int u = 0; u < 4; ++u)
#pragma unroll
                for (int v = 0; v < 4; ++v)
                    zA[u][v] = fmaf(a_[u], b_[v], zA[u][v]);
        }
        __syncthreads();
    }

    const float inv_s = 0.9999950000374997f;  // 1/sqrt(1+1e-5)
    float gs[4], bts[4], cbs[4];
#pragma unroll
    for (int v = 0; v < 4; ++v) {
        int o = o0 + tx * 4 + v;
        gs[v]  = gam[o] * inv_s;
        bts[v] = bet[o];
        cbs[v] = cb[o];
    }

    float best[4][4];
#pragma unroll
    for (int u = 0; u < 4; ++u)
#pragma unroll
        for (int v = 0; v < 4; ++v) best[u][v] = -1e30f;

    int obB = o0 - bcol0;                  // col offset within Bq rows
    for (int k = 0; k < KNN; ++k) {
#pragma unroll
        for (int u = 0; u < 4; ++u) {
            int j = jidx[(ty * 4 + u) * KNN + k];
            float bvv[4];
            if (!readBf16) {
                float4 g = *(const float4*)
                    ((const float*)Bq + (size_t)j * ldB + obB + tx * 4);
                bvv[0] = g.x; bvv[1] = g.y; bvv[2] = g.z; bvv[3] = g.w;
            } else {
                ushort4 g = *(const ushort4*)
                    ((const unsigned short*)Bq + (size_t)j * ldB + obB + tx * 4);
                bvv[0] = u2f(g.x); bvv[1] = u2f(g.y);
                bvv[2] = u2f(g.z); bvv[3] = u2f(g.w);
            }
#pragma unroll
            for (int v = 0; v < 4; ++v) {
                float z = zA[u][v] + bvv[v] + cbs[v];
                float y = fmaf(z, gs[v], bts[v]);
                float ge = 0.5f * y * (1.0f + erff(y * 0.70710678118654752f));
                best[u][v] = fmaxf(best[u][v], ge);
            }
        }
    }

#pragma unroll
    for (int v = 0; v < 4; ++v) {
        int o = o0 + tx * 4 + v;
        float4 pk = {best[0][v], best[1][v], best[2][v], best[3][v]};
        *(float4*)(out + ((size_t)(b * CO_ + o)) * NPT + n0 + ty * 4) = pk;
    }
}

// ---------------------------------------------------------------------------
// K6: regenerate edge plane1 (center indices) — clobbered by chunk-D B buf.
// ---------------------------------------------------------------------------
__global__ __launch_bounds__(256) void k_center(float* __restrict__ e1)
{
    int p = blockIdx.x * 256 + threadIdx.x;
    if (p >= NROWS * KNN) return;
    e1[p] = (float)((p / KNN) % NPT);
}

// ---------------------------------------------------------------------------
extern "C" void kernel_launch(void* const* d_in, const int* in_sizes, int n_in,
                              void* d_out, int out_size, void* d_ws, size_t ws_size,
                              hipStream_t stream)
{
    const float* x   = (const float*)d_in[0];
    const float* cw  = (const float*)d_in[1];
    const float* cb  = (const float*)d_in[2];
    const float* gam = (const float*)d_in[3];
    const float* bet = (const float*)d_in[4];

    // d_out: FLOAT32. out0 = floats [0, 4,816,896) (quarters Q_b of
    // 1,204,224 floats each = batch b's output); e0 (nn idx) =
    // [4,816,896, 4,929,792); e1 (center) = [4,929,792, 5,042,688).
    float* ou   = (float*)d_out;
    float* out0 = ou;
    double* invn64 = (double*)d_out;                       // Q0 head, dead
    double* sqd    = (double*)((char*)d_out + 100352);     //   after refine
    float*  invn32 = (float*)((char*)d_out + 200704);
    unsigned short* cand =
        (unsigned short*)((char*)d_out + 250880);          // ends @2,257,920 B
    float* e0 = ou + 4816896;
    float* e1 = ou + 4929792;

    k_norm   <<<NROWS / 256, 256, 0, stream>>>(x, invn32, invn64, sqd);
    k_screen2<<<B_ * (NPT / 32), 128, 0, stream>>>(x, invn32, cand);
    k_refine <<<NROWS / 4, 256, 0, stream>>>(x, invn64, sqd, cand, e0, e1);

    // Batches 3,2,1: full B (3136x384 fp32 = 4.8 MB) in Q0 (free until b0).
    for (int b = 3; b >= 1; --b) {
        k_gemmB<<<49 * 6, 256, 0, stream>>>(x, cw, (void*)ou, b, 0, 384, 0);
        k_outA <<<49 * 6, 256, 0, stream>>>(x, cw, e0, cb, gam, bet, out0,
                                            (const void*)ou, b, 0, 0, 384, 0);
    }
    // Batch 0 in col-chunks; B buffers in provably-dead out0-head / e1:
    //  A: cols [256,384) B fp32 @ floats [0,401,408)   out -> [802,816,1,204,224)
    //  B: cols [128,256) B fp32 @ floats [0,401,408)   out -> [401,408,  802,816)
    //  C: cols [ 64,128) B fp32 @ floats [0,200,704)   out -> [200,704,  401,408)
    //  D: cols [  0, 64) B bf16 @ e1 (401,408 B)       out -> [      0,  200,704)
    k_gemmB<<<49 * 2, 256, 0, stream>>>(x, cw, (void*)ou, 0, 256, 128, 0);
    k_outA <<<49 * 2, 256, 0, stream>>>(x, cw, e0, cb, gam, bet, out0,
                                        (const void*)ou, 0, 256, 256, 128, 0);
    k_gemmB<<<49 * 2, 256, 0, stream>>>(x, cw, (void*)ou, 0, 128, 128, 0);
    k_outA <<<49 * 2, 256, 0, stream>>>(x, cw, e0, cb, gam, bet, out0,
                                        (const void*)ou, 0, 128, 128, 128, 0);
    k_gemmB<<<49 * 1, 256, 0, stream>>>(x, cw, (void*)ou, 0, 64, 64, 0);
    k_outA <<<49 * 1, 256, 0, stream>>>(x, cw, e0, cb, gam, bet, out0,
                                        (const void*)ou, 0, 64, 64, 64, 0);
    k_gemmB<<<49 * 1, 256, 0, stream>>>(x, cw, (void*)e1, 0, 0, 64, 1);
    k_outA <<<49 * 1, 256, 0, stream>>>(x, cw, e0, cb, gam, bet, out0,
                                        (const void*)e1, 0, 0, 0, 64, 1);
    // Regenerate e1 (center plane) last.
    k_center<<<(NROWS * KNN + 255) / 256, 256, 0, stream>>>(e1);
}

// Round 10
// 1444.898 us; speedup vs baseline: 1.5342x; 1.4696x over previous
//
#include <hip/hip_runtime.h>
#include <hip/hip_bf16.h>
#include <math.h>

#define B_    4
#define C_    192
#define NPT   3136          // H*W points per batch
#define CO_   384           // Cout
#define KNN   9
#define LDEPTH 10           // per-thread screening list depth
#define CAND  64            // 4 j-chunks * merged top-16 per row
#define NROWS (B_*NPT)      // 12544 total points

__device__ __forceinline__ float u2f(unsigned short u) {
    unsigned int t = ((unsigned int)u) << 16;
    float f; __builtin_memcpy(&f, &t, 4); return f;
}
__device__ __forceinline__ unsigned short f2u(float f) {
    __hip_bfloat16 h = __float2bfloat16(f);
    unsigned short u; __builtin_memcpy(&u, &h, 2); return u;
}

// ---------------------------------------------------------------------------
// K1: per-point f64 norm stats from fp32 x.
// ---------------------------------------------------------------------------
__global__ __launch_bounds__(256) void k_norm(
    const float* __restrict__ x,
    float* __restrict__ invn32, double* __restrict__ invn64,
    double* __restrict__ sqd)
{
    int p = blockIdx.x * 256 + threadIdx.x;
    if (p >= NROWS) return;
    int b = p / NPT, n = p % NPT;
    const float* xb = x + (size_t)b * C_ * NPT + n;
    double S = 0.0;
    for (int c = 0; c < C_; ++c) {
        double v = (double)xb[(size_t)c * NPT];
        S = fma(v, v, S);
    }
    double nrm = sqrt(S);
    if (nrm < 1e-12) nrm = 1e-12;
    double iv = 1.0 / nrm;
    invn64[p] = iv;
    invn32[p] = (float)iv;
    sqd[p] = iv * iv * S;
}

// ---------------------------------------------------------------------------
// K2 v3: fp32 screening, j-split 4-way for occupancy (392 -> 1568 blocks).
//   Block = (batch, 32 rows, j-chunk). Thread = 2 rows x 8 cols.
//   XiL raw full-K rows staged once; invn_j applied at rank time only
//   (invn_i is row-constant -> same per-row ordering).
//   After the j-loop: per-row exact 8-way merge of the sorted top-10 lists
//   -> chunk top-16 -> cand[row][chunk*16+s]. Guarantee: true top-9 j has
//   <=8 better globally => in owner-thread top-10 => in merged top-16.
// ---------------------------------------------------------------------------
__global__ __launch_bounds__(128) void k_screen3(
    const float* __restrict__ x, const float* __restrict__ invn32,
    unsigned short* __restrict__ cand)
{
    __shared__ __align__(16) char smem[33024];
    float (*XiL)[32] = (float(*)[32])smem;              // [192][32] 24,576 B
    float (*Xj)[64]  = (float(*)[64])(smem + 24576);    // [32][64]   8,192 B
    float* sJ        = (float*)(smem + 32768);          // [64]         256 B

    int blk  = blockIdx.x;
    int chunk = blk & 3;
    int t2    = blk >> 2;
    int b  = t2 / 98;
    int i0 = (t2 % 98) * 32;
    int j0base = chunk * 768;
    int ntiles = (chunk == 3) ? 13 : 12;     // 768,768,768,832
    int tid = threadIdx.x;
    int ty = tid >> 3;                // 0..15 -> rows 2ty, 2ty+1
    int tx = tid & 7;                 // cols tx*8..tx*8+7 of each j-tile
    const float* xb = x + (size_t)b * C_ * NPT;

    // stage XiL: 6144 floats = 1536 float4 / 128 thr = 12 iters
#pragma unroll
    for (int e = 0; e < 12; ++e) {
        int q = tid + e * 128;
        int cc = q >> 3, r4 = (q & 7) * 4;
        *(float4*)&XiL[cc][r4] = *(const float4*)&xb[(size_t)cc * NPT + i0 + r4];
    }

    float bd[2][LDEPTH];
    int   bi[2][LDEPTH];
#pragma unroll
    for (int r = 0; r < 2; ++r)
#pragma unroll
        for (int q = 0; q < LDEPTH; ++q) { bd[r][q] = -1e30f; bi[r][q] = 0; }

    for (int jt = 0; jt < ntiles; ++jt) {
        int j0 = j0base + jt * 64;
        float a0[8], a1[8];
#pragma unroll
        for (int k = 0; k < 8; ++k) { a0[k] = 0.f; a1[k] = 0.f; }
        float sjv[8];

        for (int ct = 0; ct < 6; ++ct) {
            int c0 = ct * 32;
#pragma unroll
            for (int e = 0; e < 4; ++e) {
                int q = tid + e * 128;
                int cc = q >> 4, j4 = (q & 15) * 4;
                *(float4*)&Xj[cc][j4] =
                    *(const float4*)&xb[(size_t)(c0 + cc) * NPT + j0 + j4];
            }
            if (ct == 0 && tid < 64) sJ[tid] = invn32[(size_t)b * NPT + j0 + tid];
            __syncthreads();
            if (ct == 0) {
#pragma unroll
                for (int k = 0; k < 8; ++k) sjv[k] = sJ[tx * 8 + k];
            }
#pragma unroll
            for (int cc = 0; cc < 32; ++cc) {
                float2 xi = *(const float2*)&XiL[c0 + cc][ty * 2];
                const float4* xjv = (const float4*)&Xj[cc][tx * 8];
                float4 v0 = xjv[0], v1 = xjv[1];
                a0[0] = fmaf(xi.x, v0.x, a0[0]); a1[0] = fmaf(xi.y, v0.x, a1[0]);
                a0[1] = fmaf(xi.x, v0.y, a0[1]); a1[1] = fmaf(xi.y, v0.y, a1[1]);
                a0[2] = fmaf(xi.x, v0.z, a0[2]); a1[2] = fmaf(xi.y, v0.z, a1[2]);
                a0[3] = fmaf(xi.x, v0.w, a0[3]); a1[3] = fmaf(xi.y, v0.w, a1[3]);
                a0[4] = fmaf(xi.x, v1.x, a0[4]); a1[4] = fmaf(xi.y, v1.x, a1[4]);
                a0[5] = fmaf(xi.x, v1.y, a0[5]); a1[5] = fmaf(xi.y, v1.y, a1[5]);
                a0[6] = fmaf(xi.x, v1.z, a0[6]); a1[6] = fmaf(xi.y, v1.z, a1[6]);
                a0[7] = fmaf(xi.x, v1.w, a0[7]); a1[7] = fmaf(xi.y, v1.w, a1[7]);
            }
            __syncthreads();
        }
#pragma unroll
        for (int k = 0; k < 8; ++k) {
            float d0 = a0[k] * sjv[k];
            int   jj = j0 + tx * 8 + k;
            if (d0 > bd[0][LDEPTH - 1]) {
                bd[0][LDEPTH - 1] = d0; bi[0][LDEPTH - 1] = jj;
#pragma unroll
                for (int q = LDEPTH - 1; q > 0; --q)
                    if (bd[0][q] > bd[0][q - 1]) {
                        float td = bd[0][q]; bd[0][q] = bd[0][q-1]; bd[0][q-1] = td;
                        int   tj = bi[0][q]; bi[0][q] = bi[0][q-1]; bi[0][q-1] = tj;
                    }
            }
            float d1 = a1[k] * sjv[k];
            if (d1 > bd[1][LDEPTH - 1]) {
                bd[1][LDEPTH - 1] = d1; bi[1][LDEPTH - 1] = jj;
#pragma unroll
                for (int q = LDEPTH - 1; q > 0; --q)
                    if (bd[1][q] > bd[1][q - 1]) {
                        float td = bd[1][q]; bd[1][q] = bd[1][q-1]; bd[1][q-1] = td;
                        int   tj = bi[1][q]; bi[1][q] = bi[1][q-1]; bi[1][q-1] = tj;
                    }
            }
        }
    }

    // ---- per-row exact merge of 8 sorted lists -> chunk top-16 ----
    __syncthreads();                      // XiL/Xj dead; repurpose smem
    float* md = (float*)smem;             // [32][81] padded (conflict-free)
    int*   mi = (int*)(smem + 32 * 81 * 4);
    int r0 = 2 * ty;
#pragma unroll
    for (int r = 0; r < 2; ++r)
#pragma unroll
        for (int q = 0; q < LDEPTH; ++q) {
            md[(r0 + r) * 81 + tx * LDEPTH + q] = bd[r][q];
            mi[(r0 + r) * 81 + tx * LDEPTH + q] = bi[r][q];
        }
    __syncthreads();
    if (tid < 32) {
        int h[8];
#pragma unroll
        for (int g = 0; g < 8; ++g) h[g] = 0;
        unsigned short* cp =
            cand + ((size_t)b * NPT + i0 + tid) * CAND + chunk * 16;
        const float* rd = md + tid * 81;
        const int*   ri = mi + tid * 81;
        for (int s = 0; s < 16; ++s) {
            float best = -2e30f; int bg = 0;
#pragma unroll
            for (int g = 0; g < 8; ++g) {
                float v = (h[g] < LDEPTH) ? rd[g * LDEPTH + h[g]] : -2e30f;
                if (v > best) { best = v; bg = g; }
            }
            cp[s] = (unsigned short)ri[bg * LDEPTH + h[bg]];
            h[bg]++;
        }
    }
}

// ---------------------------------------------------------------------------
// K3: f64 refine of 64 candidates/row; exact top-9 (dist asc, idx asc);
//     writes edge plane0 (nn idx) and plane1 (center) as fp32.
// ---------------------------------------------------------------------------
__global__ __launch_bounds__(256) void k_refine(
    const float* __restrict__ x, const double* __restrict__ invn64,
    const double* __restrict__ sqd, const unsigned short* __restrict__ cand,
    float* __restrict__ e0, float* __restrict__ e1)
{
    __shared__ double dbuf[4][CAND];
    __shared__ int    icand[4][CAND];
    int wave = threadIdx.x >> 6;
    int lane = threadIdx.x & 63;
    int row  = blockIdx.x * 4 + wave;
    int b    = row / NPT, i = row % NPT;

    icand[wave][lane] = (int)cand[(size_t)row * CAND + lane];
    __syncthreads();

    int sub = lane & 7, cg = lane >> 3;
    const float* xb = x + (size_t)b * C_ * NPT;
    double xif[24];
#pragma unroll
    for (int q = 0; q < 24; ++q)
        xif[q] = (double)xb[(size_t)(sub * 24 + q) * NPT + i];
    double ivi = invn64[row], sqi = sqd[row];

    for (int cc = 0; cc < CAND / 8; ++cc) {
        int cidx = cc * 8 + cg;
        int j = icand[wave][cidx];
        double dot = 0.0;
#pragma unroll
        for (int q = 0; q < 24; ++q)
            dot = fma(xif[q], (double)xb[(size_t)(sub * 24 + q) * NPT + j], dot);
        dot += __shfl_xor(dot, 1);
        dot += __shfl_xor(dot, 2);
        dot += __shfl_xor(dot, 4);
        if (sub == 0)
            dbuf[wave][cidx] = sqi + sqd[(size_t)b * NPT + j]
                             - 2.0 * (ivi * invn64[(size_t)b * NPT + j] * dot);
    }
    __syncthreads();

    if (lane == 0) {
        float* p0 = e0 + (size_t)row * KNN;
        float* p1 = e1 + (size_t)row * KNN;
        for (int q = 0; q < KNN; ++q) {
            double best = 1e300; int bj = 0x7fffffff; int bc = 0;
            for (int t = 0; t < CAND; ++t) {
                double d = dbuf[wave][t]; int j = icand[wave][t];
                if (d < best || (d == best && j < bj)) { best = d; bj = j; bc = t; }
            }
            dbuf[wave][bc] = 1e301;
            p0[q] = (float)bj;
            p1[q] = (float)i;
        }
    }
}

// ---------------------------------------------------------------------------
// K4: B = W2 * x for one batch, cols [bcol0, bcol0 + gridDim/49*64).
//     Bq row-major [n][ldB]; fp32 or bf16 per storeBf16.
// ---------------------------------------------------------------------------
__global__ __launch_bounds__(256) void k_gemmB(
    const float* __restrict__ x, const float* __restrict__ cw,
    void* __restrict__ Bq, int b, int bcol0, int ldB, int storeBf16)
{
    __shared__ float Xt[16][68];
    __shared__ float Wt[16][68];
    int bm = blockIdx.x % 49;
    int bo = blockIdx.x / 49;
    int m0 = bm * 64;
    int tid = threadIdx.x;
    int tx = tid & 15, ty = tid >> 4;
    const float* xb = x + (size_t)b * C_ * NPT;
    float acc[4][4];
#pragma unroll
    for (int u = 0; u < 4; ++u)
#pragma unroll
        for (int v = 0; v < 4; ++v) acc[u][v] = 0.f;

    for (int ct = 0; ct < 12; ++ct) {
        int c0 = ct * 16;
        {
            int cc = tid >> 4, n4 = (tid & 15) * 4;
            *(float4*)&Xt[cc][n4] =
                *(const float4*)&xb[(size_t)(c0 + cc) * NPT + m0 + n4];
        }
        {
            int oo = tid >> 2, c4 = (tid & 3) * 4;
            int o = bcol0 + bo * 64 + oo;
            float4 w = *(const float4*)&cw[(size_t)o * 384 + C_ + c0 + c4];
            Wt[c4 + 0][oo] = w.x; Wt[c4 + 1][oo] = w.y;
            Wt[c4 + 2][oo] = w.z; Wt[c4 + 3][oo] = w.w;
        }
        __syncthreads();
#pragma unroll
        for (int cc = 0; cc < 16; ++cc) {
            float4 av = *(const float4*)&Xt[cc][ty * 4];
            float4 bv = *(const float4*)&Wt[cc][tx * 4];
            float a_[4] = {av.x, av.y, av.z, av.w};
            float b_[4] = {bv.x, bv.y, bv.z, bv.w};
#pragma unroll
            for (int u = 0; u < 4; ++u)
#pragma unroll
                for (int v = 0; v < 4; ++v)
                    acc[u][v] = fmaf(a_[u], b_[v], acc[u][v]);
        }
        __syncthreads();
    }
    if (!storeBf16) {
        float* Bf = (float*)Bq;
#pragma unroll
        for (int u = 0; u < 4; ++u) {
            float4 pk = {acc[u][0], acc[u][1], acc[u][2], acc[u][3]};
            *(float4*)&Bf[(size_t)(m0 + ty * 4 + u) * ldB + bo * 64 + tx * 4] = pk;
        }
    } else {
        unsigned short* Bh = (unsigned short*)Bq;
#pragma unroll
        for (int u = 0; u < 4; ++u) {
            ushort4 pk;
            pk.x = f2u(acc[u][0]); pk.y = f2u(acc[u][1]);
            pk.z = f2u(acc[u][2]); pk.w = f2u(acc[u][3]);
            *(ushort4*)&Bh[(size_t)(m0 + ty * 4 + u) * ldB + bo * 64 + tx * 4] = pk;
        }
    }
}

// ---------------------------------------------------------------------------
// K5: epilogue. zA = (W1-W2) x_i (on-the-fly GEMM); per k gather B_j row;
//     z = zA + B + cb; BN; gelu; online max over 9; store fp32.
// ---------------------------------------------------------------------------
__global__ __launch_bounds__(256) void k_outA(
    const float* __restrict__ x, const float* __restrict__ cw,
    const float* __restrict__ e0, const float* __restrict__ cb,
    const float* __restrict__ gam, const float* __restrict__ bet,
    float* __restrict__ out, const void* __restrict__ Bq,
    int b, int o0base, int bcol0, int ldB, int readBf16)
{
    __shared__ float Xi[16][68];
    __shared__ float Wd[16][68];
    __shared__ int jidx[64 * KNN];
    int r  = blockIdx.x;
    int nt = r % 49, ot = r / 49;
    int n0 = nt * 64, o0 = o0base + ot * 64;
    int tid = threadIdx.x;
    int tx = tid & 15, ty = tid >> 4;
    const float* xb = x + (size_t)b * C_ * NPT;

    for (int e = tid; e < 64 * KNN; e += 256)
        jidx[e] = (int)e0[((size_t)b * NPT + n0 + e / KNN) * KNN + e % KNN];

    float zA[4][4];
#pragma unroll
    for (int u = 0; u < 4; ++u)
#pragma unroll
        for (int v = 0; v < 4; ++v) zA[u][v] = 0.f;

    for (int ct = 0; ct < 12; ++ct) {
        int c0 = ct * 16;
        {
            int cc = tid >> 4, n4 = (tid & 15) * 4;
            *(float4*)&Xi[cc][n4] =
                *(const float4*)&xb[(size_t)(c0 + cc) * NPT + n0 + n4];
        }
        {
            int oo = tid >> 2, c4 = (tid & 3) * 4;
            int o = o0 + oo;
            float4 w1 = *(const float4*)&cw[(size_t)o * 384 + c0 + c4];
            float4 w2 = *(const float4*)&cw[(size_t)o * 384 + C_ + c0 + c4];
            Wd[c4 + 0][oo] = w1.x - w2.x; Wd[c4 + 1][oo] = w1.y - w2.y;
            Wd[c4 + 2][oo] = w1.z - w2.z; Wd[c4 + 3][oo] = w1.w - w2.w;
        }
        __syncthreads();
#pragma unroll
        for (int cc = 0; cc < 16; ++cc) {
            float4 av = *(const float4*)&Xi[cc][ty * 4];
            float4 bv = *(const float4*)&Wd[cc][tx * 4];
            float a_[4] = {av.x, av.y, av.z, av.w};
            float b_[4] = {bv.x, bv.y, bv.z, bv.w};
#pragma unroll
            for (int u = 0; u < 4; ++u)
#pragma unroll
                for (int v = 0; v < 4; ++v)
                    zA[u][v] = fmaf(a_[u], b_[v], zA[u][v]);
        }
        __syncthreads();
    }

    const float inv_s = 0.9999950000374997f;  // 1/sqrt(1+1e-5)
    float gs[4], bts[4], cbs[4];
#pragma unroll
    for (int v = 0; v < 4; ++v) {
        int o = o0 + tx * 4 + v;
        gs[v]  = gam[o] * inv_s;
        bts[v] = bet[o];
        cbs[v] = cb[o];
    }

    float best[4][4];
#pragma unroll
    for (int u = 0; u < 4; ++u)
#pragma unroll
        for (int v = 0; v < 4; ++v) best[u][v] = -1e30f;

    int obB = o0 - bcol0;                  // col offset within Bq rows
    for (int k = 0; k < KNN; ++k) {
#pragma unroll
        for (int u = 0; u < 4; ++u) {
            int j = jidx[(ty * 4 + u) * KNN + k];
            float bvv[4];
            if (!readBf16) {
                float4 g = *(const float4*)
                    ((const float*)Bq + (size_t)j * ldB + obB + tx * 4);
                bvv[0] = g.x; bvv[1] = g.y; bvv[2] = g.z; bvv[3] = g.w;
            } else {
                ushort4 g = *(const ushort4*)
                    ((const unsigned short*)Bq + (size_t)j * ldB + obB + tx * 4);
                bvv[0] = u2f(g.x); bvv[1] = u2f(g.y);
                bvv[2] = u2f(g.z); bvv[3] = u2f(g.w);
            }
#pragma unroll
            for (int v = 0; v < 4; ++v) {
                float z = zA[u][v] + bvv[v] + cbs[v];
                float y = fmaf(z, gs[v], bts[v]);
                float ge = 0.5f * y * (1.0f + erff(y * 0.70710678118654752f));
                best[u][v] = fmaxf(best[u][v], ge);
            }
        }
    }

#pragma unroll
    for (int v = 0; v < 4; ++v) {
        int o = o0 + tx * 4 + v;
        float4 pk = {best[0][v], best[1][v], best[2][v], best[3][v]};
        *(float4*)(out + ((size_t)(b * CO_ + o)) * NPT + n0 + ty * 4) = pk;
    }
}

// ---------------------------------------------------------------------------
// K6: regenerate edge plane1 (center indices) — clobbered by chunk-C B buf.
// ---------------------------------------------------------------------------
__global__ __launch_bounds__(256) void k_center(float* __restrict__ e1)
{
    int p = blockIdx.x * 256 + threadIdx.x;
    if (p >= NROWS * KNN) return;
    e1[p] = (float)((p / KNN) % NPT);
}

// ---------------------------------------------------------------------------
extern "C" void kernel_launch(void* const* d_in, const int* in_sizes, int n_in,
                              void* d_out, int out_size, void* d_ws, size_t ws_size,
                              hipStream_t stream)
{
    const float* x   = (const float*)d_in[0];
    const float* cw  = (const float*)d_in[1];
    const float* cb  = (const float*)d_in[2];
    const float* gam = (const float*)d_in[3];
    const float* bet = (const float*)d_in[4];

    // d_out: FLOAT32. out0 = floats [0, 4,816,896) (quarters Q_b of
    // 1,204,224 floats = batch b's output); e0 (nn idx) =
    // [4,816,896, 4,929,792); e1 (center) = [4,929,792, 5,042,688).
    float* ou   = (float*)d_out;
    float* out0 = ou;
    double* invn64 = (double*)d_out;                       // Q0 head, dead
    double* sqd    = (double*)((char*)d_out + 100352);     //   after refine
    float*  invn32 = (float*)((char*)d_out + 200704);
    unsigned short* cand =
        (unsigned short*)((char*)d_out + 250880);          // 1,605,632 B
    float* e0 = ou + 4816896;
    float* e1 = ou + 4929792;

    k_norm   <<<NROWS / 256, 256, 0, stream>>>(x, invn32, invn64, sqd);
    k_screen3<<<B_ * 98 * 4, 128, 0, stream>>>(x, invn32, cand);
    k_refine <<<NROWS / 4, 256, 0, stream>>>(x, invn64, sqd, cand, e0, e1);

    // Batches 3,2,1: full B (3136x384 fp32 = 4.8 MB) in Q0 (free until b0).
    for (int b = 3; b >= 1; --b) {
        k_gemmB<<<49 * 6, 256, 0, stream>>>(x, cw, (void*)ou, b, 0, 384, 0);
        k_outA <<<49 * 6, 256, 0, stream>>>(x, cw, e0, cb, gam, bet, out0,
                                            (const void*)ou, b, 0, 0, 384, 0);
    }
    // Batch 0 in 3 bf16 col-chunks; B buffers in provably-dead space:
    //  1: cols [192,384) B bf16 @ Q0 bytes [0,1,204,224) out->[2,408,448,4,816,896)
    //  2: cols [ 64,192) B bf16 @ Q0 bytes [0,  802,816) out->[  802,816,2,408,448)
    //  3: cols [  0, 64) B bf16 @ e1      (401,408 B)    out->[        0,  802,816)
    k_gemmB<<<49 * 3, 256, 0, stream>>>(x, cw, (void*)ou, 0, 192, 192, 1);
    k_outA <<<49 * 3, 256, 0, stream>>>(x, cw, e0, cb, gam, bet, out0,
                                        (const void*)ou, 0, 192, 192, 192, 1);
    k_gemmB<<<49 * 2, 256, 0, stream>>>(x, cw, (void*)ou, 0, 64, 128, 1);
    k_outA <<<49 * 2, 256, 0, stream>>>(x, cw, e0, cb, gam, bet, out0,
                                        (const void*)ou, 0, 64, 64, 128, 1);
    k_gemmB<<<49 * 1, 256, 0, stream>>>(x, cw, (void*)e1, 0, 0, 64, 1);
    k_outA <<<49 * 1, 256, 0, stream>>>(x, cw, e0, cb, gam, bet, out0,
                                        (const void*)e1, 0, 0, 0, 64, 1);
    // Regenerate e1 (center plane) last.
    k_center<<<(NROWS * KNN + 255) / 256, 256, 0, stream>>>(e1);
}

// Round 11
// 916.669 us; speedup vs baseline: 2.4183x; 1.5762x over previous
//
#include <hip/hip_runtime.h>
#include <hip/hip_bf16.h>
#include <math.h>

#define B_    4
#define C_    192
#define NPT   3136          // H*W points per batch
#define CO_   384           // Cout
#define KNN   9
#define LDEPTH 10           // per-thread screening list depth
#define CAND  64            // 4 j-chunks * merged top-16 per row
#define NROWS (B_*NPT)      // 12544 total points

__device__ __forceinline__ float u2f(unsigned short u) {
    unsigned int t = ((unsigned int)u) << 16;
    float f; __builtin_memcpy(&f, &t, 4); return f;
}
__device__ __forceinline__ unsigned short f2u(float f) {
    __hip_bfloat16 h = __float2bfloat16(f);
    unsigned short u; __builtin_memcpy(&u, &h, 2); return u;
}

// ---------------------------------------------------------------------------
// K1: per-point f64 norm stats from fp32 x.
// ---------------------------------------------------------------------------
__global__ __launch_bounds__(256) void k_norm(
    const float* __restrict__ x,
    float* __restrict__ invn32, double* __restrict__ invn64,
    double* __restrict__ sqd)
{
    int p = blockIdx.x * 256 + threadIdx.x;
    if (p >= NROWS) return;
    int b = p / NPT, n = p % NPT;
    const float* xb = x + (size_t)b * C_ * NPT + n;
    double S = 0.0;
    for (int c = 0; c < C_; ++c) {
        double v = (double)xb[(size_t)c * NPT];
        S = fma(v, v, S);
    }
    double nrm = sqrt(S);
    if (nrm < 1e-12) nrm = 1e-12;
    double iv = 1.0 / nrm;
    invn64[p] = iv;
    invn32[p] = (float)iv;
    sqd[p] = iv * iv * S;
}

// ---------------------------------------------------------------------------
// K1b: LDS-tiled transpose x [b][c][n] -> xT [b*NPT+n][c] (fp32, exact).
// ---------------------------------------------------------------------------
__global__ __launch_bounds__(256) void k_xpose(
    const float* __restrict__ x, float* __restrict__ xT)
{
    __shared__ float t[32][33];
    int blk = blockIdx.x;
    int b  = blk / 588;
    int r  = blk % 588;
    int ct = r / 98, nt = r % 98;
    int c0 = ct * 32, n0 = nt * 32;
    int tid = threadIdx.x;
    int tx = tid & 31, ty8 = tid >> 5;          // 8 rows per pass
    const float* xb = x + (size_t)b * C_ * NPT;
#pragma unroll
    for (int e = 0; e < 4; ++e) {
        int cc = ty8 + e * 8;
        t[cc][tx] = xb[(size_t)(c0 + cc) * NPT + n0 + tx];
    }
    __syncthreads();
#pragma unroll
    for (int e = 0; e < 4; ++e) {
        int nn = ty8 + e * 8;
        xT[(size_t)(b * NPT + n0 + nn) * C_ + c0 + tx] = t[tx][nn];
    }
}

// ---------------------------------------------------------------------------
// K2 v3: fp32 screening, j-split 4-way (1568 blocks). Unchanged from R10.
// ---------------------------------------------------------------------------
__global__ __launch_bounds__(128) void k_screen3(
    const float* __restrict__ x, const float* __restrict__ invn32,
    unsigned short* __restrict__ cand)
{
    __shared__ __align__(16) char smem[33024];
    float (*XiL)[32] = (float(*)[32])smem;              // [192][32] 24,576 B
    float (*Xj)[64]  = (float(*)[64])(smem + 24576);    // [32][64]   8,192 B
    float* sJ        = (float*)(smem + 32768);          // [64]         256 B

    int blk  = blockIdx.x;
    int chunk = blk & 3;
    int t2    = blk >> 2;
    int b  = t2 / 98;
    int i0 = (t2 % 98) * 32;
    int j0base = chunk * 768;
    int ntiles = (chunk == 3) ? 13 : 12;     // 768,768,768,832
    int tid = threadIdx.x;
    int ty = tid >> 3;
    int tx = tid & 7;
    const float* xb = x + (size_t)b * C_ * NPT;

#pragma unroll
    for (int e = 0; e < 12; ++e) {
        int q = tid + e * 128;
        int cc = q >> 3, r4 = (q & 7) * 4;
        *(float4*)&XiL[cc][r4] = *(const float4*)&xb[(size_t)cc * NPT + i0 + r4];
    }

    float bd[2][LDEPTH];
    int   bi[2][LDEPTH];
#pragma unroll
    for (int r = 0; r < 2; ++r)
#pragma unroll
        for (int q = 0; q < LDEPTH; ++q) { bd[r][q] = -1e30f; bi[r][q] = 0; }

    for (int jt = 0; jt < ntiles; ++jt) {
        int j0 = j0base + jt * 64;
        float a0[8], a1[8];
#pragma unroll
        for (int k = 0; k < 8; ++k) { a0[k] = 0.f; a1[k] = 0.f; }
        float sjv[8];

        for (int ct = 0; ct < 6; ++ct) {
            int c0 = ct * 32;
#pragma unroll
            for (int e = 0; e < 4; ++e) {
                int q = tid + e * 128;
                int cc = q >> 4, j4 = (q & 15) * 4;
                *(float4*)&Xj[cc][j4] =
                    *(const float4*)&xb[(size_t)(c0 + cc) * NPT + j0 + j4];
            }
            if (ct == 0 && tid < 64) sJ[tid] = invn32[(size_t)b * NPT + j0 + tid];
            __syncthreads();
            if (ct == 0) {
#pragma unroll
                for (int k = 0; k < 8; ++k) sjv[k] = sJ[tx * 8 + k];
            }
#pragma unroll
            for (int cc = 0; cc < 32; ++cc) {
                float2 xi = *(const float2*)&XiL[c0 + cc][ty * 2];
                const float4* xjv = (const float4*)&Xj[cc][tx * 8];
                float4 v0 = xjv[0], v1 = xjv[1];
                a0[0] = fmaf(xi.x, v0.x, a0[0]); a1[0] = fmaf(xi.y, v0.x, a1[0]);
                a0[1] = fmaf(xi.x, v0.y, a0[1]); a1[1] = fmaf(xi.y, v0.y, a1[1]);
                a0[2] = fmaf(xi.x, v0.z, a0[2]); a1[2] = fmaf(xi.y, v0.z, a1[2]);
                a0[3] = fmaf(xi.x, v0.w, a0[3]); a1[3] = fmaf(xi.y, v0.w, a1[3]);
                a0[4] = fmaf(xi.x, v1.x, a0[4]); a1[4] = fmaf(xi.y, v1.x, a1[4]);
                a0[5] = fmaf(xi.x, v1.y, a0[5]); a1[5] = fmaf(xi.y, v1.y, a1[5]);
                a0[6] = fmaf(xi.x, v1.z, a0[6]); a1[6] = fmaf(xi.y, v1.z, a1[6]);
                a0[7] = fmaf(xi.x, v1.w, a0[7]); a1[7] = fmaf(xi.y, v1.w, a1[7]);
            }
            __syncthreads();
        }
#pragma unroll
        for (int k = 0; k < 8; ++k) {
            float d0 = a0[k] * sjv[k];
            int   jj = j0 + tx * 8 + k;
            if (d0 > bd[0][LDEPTH - 1]) {
                bd[0][LDEPTH - 1] = d0; bi[0][LDEPTH - 1] = jj;
#pragma unroll
                for (int q = LDEPTH - 1; q > 0; --q)
                    if (bd[0][q] > bd[0][q - 1]) {
                        float td = bd[0][q]; bd[0][q] = bd[0][q-1]; bd[0][q-1] = td;
                        int   tj = bi[0][q]; bi[0][q] = bi[0][q-1]; bi[0][q-1] = tj;
                    }
            }
            float d1 = a1[k] * sjv[k];
            if (d1 > bd[1][LDEPTH - 1]) {
                bd[1][LDEPTH - 1] = d1; bi[1][LDEPTH - 1] = jj;
#pragma unroll
                for (int q = LDEPTH - 1; q > 0; --q)
                    if (bd[1][q] > bd[1][q - 1]) {
                        float td = bd[1][q]; bd[1][q] = bd[1][q-1]; bd[1][q-1] = td;
                        int   tj = bi[1][q]; bi[1][q] = bi[1][q-1]; bi[1][q-1] = tj;
                    }
            }
        }
    }

    __syncthreads();
    float* md = (float*)smem;             // [32][81] padded
    int*   mi = (int*)(smem + 32 * 81 * 4);
    int r0 = 2 * ty;
#pragma unroll
    for (int r = 0; r < 2; ++r)
#pragma unroll
        for (int q = 0; q < LDEPTH; ++q) {
            md[(r0 + r) * 81 + tx * LDEPTH + q] = bd[r][q];
            mi[(r0 + r) * 81 + tx * LDEPTH + q] = bi[r][q];
        }
    __syncthreads();
    if (tid < 32) {
        int h[8];
#pragma unroll
        for (int g = 0; g < 8; ++g) h[g] = 0;
        unsigned short* cp =
            cand + ((size_t)b * NPT + i0 + tid) * CAND + chunk * 16;
        const float* rd = md + tid * 81;
        const int*   ri = mi + tid * 81;
        for (int s = 0; s < 16; ++s) {
            float best = -2e30f; int bg = 0;
#pragma unroll
            for (int g = 0; g < 8; ++g) {
                float v = (h[g] < LDEPTH) ? rd[g * LDEPTH + h[g]] : -2e30f;
                if (v > best) { best = v; bg = g; }
            }
            cp[s] = (unsigned short)ri[bg * LDEPTH + h[bg]];
            h[bg]++;
        }
    }
}

// ---------------------------------------------------------------------------
// K3 v2: f64 refine from xT (coalesced 128B segments per 8-lane group).
//   Lane sub covers channels {q*32 + sub*4 + t}; full dot via 3 shuffles.
//   Selection: wave-wide argmin butterfly (dist asc, idx asc) — 9 rounds.
// ---------------------------------------------------------------------------
__global__ __launch_bounds__(256) void k_refine(
    const float* __restrict__ xT, const double* __restrict__ invn64,
    const double* __restrict__ sqd, const unsigned short* __restrict__ cand,
    float* __restrict__ e0)
{
    __shared__ double dbuf[4][CAND];
    __shared__ int    icand[4][CAND];
    int wave = threadIdx.x >> 6;
    int lane = threadIdx.x & 63;
    int row  = blockIdx.x * 4 + wave;
    int b    = row / NPT;

    icand[wave][lane] = (int)cand[(size_t)row * CAND + lane];
    __syncthreads();

    int sub = lane & 7, cg = lane >> 3;
    const float* xiRow = xT + (size_t)row * C_;
    float4 xif[6];
#pragma unroll
    for (int q = 0; q < 6; ++q)
        xif[q] = *(const float4*)&xiRow[q * 32 + sub * 4];
    double ivi = invn64[row], sqi = sqd[row];

    for (int cc = 0; cc < CAND / 8; ++cc) {
        int cidx = cc * 8 + cg;
        int j = icand[wave][cidx];
        const float* xjRow = xT + (size_t)(b * NPT + j) * C_;
        float4 v[6];
#pragma unroll
        for (int q = 0; q < 6; ++q)
            v[q] = *(const float4*)&xjRow[q * 32 + sub * 4];
        double d0 = 0.0, d1 = 0.0, d2 = 0.0, d3 = 0.0;
#pragma unroll
        for (int q = 0; q < 6; ++q) {
            d0 = fma((double)xif[q].x, (double)v[q].x, d0);
            d1 = fma((double)xif[q].y, (double)v[q].y, d1);
            d2 = fma((double)xif[q].z, (double)v[q].z, d2);
            d3 = fma((double)xif[q].w, (double)v[q].w, d3);
        }
        double dot = (d0 + d1) + (d2 + d3);
        dot += __shfl_xor(dot, 1);
        dot += __shfl_xor(dot, 2);
        dot += __shfl_xor(dot, 4);
        if (sub == 0)
            dbuf[wave][cidx] = sqi + sqd[(size_t)b * NPT + j]
                             - 2.0 * (ivi * invn64[(size_t)b * NPT + j] * dot);
    }
    __syncthreads();

    // wave-parallel top-9: lane <-> candidate (all 64 j distinct by constr.)
    double d = dbuf[wave][lane];
    int    j = icand[wave][lane];
    float* p0 = e0 + (size_t)row * KNN;
    for (int q = 0; q < KNN; ++q) {
        double bdv = d; int bjv = j;
#pragma unroll
        for (int off = 32; off > 0; off >>= 1) {
            double od = __shfl_xor(bdv, off);
            int    oj = __shfl_xor(bjv, off);
            if (od < bdv || (od == bdv && oj < bjv)) { bdv = od; bjv = oj; }
        }
        if (lane == 0) p0[q] = (float)bjv;
        if (j == bjv) d = 1e301;
    }
}

// ---------------------------------------------------------------------------
// K4: B = W2 * x for one batch, cols [bcol0, ...). Unchanged from R10.
// ---------------------------------------------------------------------------
__global__ __launch_bounds__(256) void k_gemmB(
    const float* __restrict__ x, const float* __restrict__ cw,
    void* __restrict__ Bq, int b, int bcol0, int ldB, int storeBf16)
{
    __shared__ float Xt[16][68];
    __shared__ float Wt[16][68];
    int bm = blockIdx.x % 49;
    int bo = blockIdx.x / 49;
    int m0 = bm * 64;
    int tid = threadIdx.x;
    int tx = tid & 15, ty = tid >> 4;
    const float* xb = x + (size_t)b * C_ * NPT;
    float acc[4][4];
#pragma unroll
    for (int u = 0; u < 4; ++u)
#pragma unroll
        for (int v = 0; v < 4; ++v) acc[u][v] = 0.f;

    for (int ct = 0; ct < 12; ++ct) {
        int c0 = ct * 16;
        {
            int cc = tid >> 4, n4 = (tid & 15) * 4;
            *(float4*)&Xt[cc][n4] =
                *(const float4*)&xb[(size_t)(c0 + cc) * NPT + m0 + n4];
        }
        {
            int oo = tid >> 2, c4 = (tid & 3) * 4;
            int o = bcol0 + bo * 64 + oo;
            float4 w = *(const float4*)&cw[(size_t)o * 384 + C_ + c0 + c4];
            Wt[c4 + 0][oo] = w.x; Wt[c4 + 1][oo] = w.y;
            Wt[c4 + 2][oo] = w.z; Wt[c4 + 3][oo] = w.w;
        }
        __syncthreads();
#pragma unroll
        for (int cc = 0; cc < 16; ++cc) {
            float4 av = *(const float4*)&Xt[cc][ty * 4];
            float4 bv = *(const float4*)&Wt[cc][tx * 4];
            float a_[4] = {av.x, av.y, av.z, av.w};
            float b_[4] = {bv.x, bv.y, bv.z, bv.w};
#pragma unroll
            for (int u = 0; u < 4; ++u)
#pragma unroll
                for (int v = 0; v < 4; ++v)
                    acc[u][v] = fmaf(a_[u], b_[v], acc[u][v]);
        }
        __syncthreads();
    }
    if (!storeBf16) {
        float* Bf = (float*)Bq;
#pragma unroll
        for (int u = 0; u < 4; ++u) {
            float4 pk = {acc[u][0], acc[u][1], acc[u][2], acc[u][3]};
            *(float4*)&Bf[(size_t)(m0 + ty * 4 + u) * ldB + bo * 64 + tx * 4] = pk;
        }
    } else {
        unsigned short* Bh = (unsigned short*)Bq;
#pragma unroll
        for (int u = 0; u < 4; ++u) {
            ushort4 pk;
            pk.x = f2u(acc[u][0]); pk.y = f2u(acc[u][1]);
            pk.z = f2u(acc[u][2]); pk.w = f2u(acc[u][3]);
            *(ushort4*)&Bh[(size_t)(m0 + ty * 4 + u) * ldB + bo * 64 + tx * 4] = pk;
        }
    }
}

// ---------------------------------------------------------------------------
// K5: epilogue. Unchanged from R10.
// ---------------------------------------------------------------------------
__global__ __launch_bounds__(256) void k_outA(
    const float* __restrict__ x, const float* __restrict__ cw,
    const float* __restrict__ e0, const float* __restrict__ cb,
    const float* __restrict__ gam, const float* __restrict__ bet,
    float* __restrict__ out, const void* __restrict__ Bq,
    int b, int o0base, int bcol0, int ldB, int readBf16)
{
    __shared__ float Xi[16][68];
    __shared__ float Wd[16][68];
    __shared__ int jidx[64 * KNN];
    int r  = blockIdx.x;
    int nt = r % 49, ot = r / 49;
    int n0 = nt * 64, o0 = o0base + ot * 64;
    int tid = threadIdx.x;
    int tx = tid & 15, ty = tid >> 4;
    const float* xb = x + (size_t)b * C_ * NPT;

    for (int e = tid; e < 64 * KNN; e += 256)
        jidx[e] = (int)e0[((size_t)b * NPT + n0 + e / KNN) * KNN + e % KNN];

    float zA[4][4];
#pragma unroll
    for (int u = 0; u < 4; ++u)
#pragma unroll
        for (int v = 0; v < 4; ++v) zA[u][v] = 0.f;

    for (int ct = 0; ct < 12; ++ct) {
        int c0 = ct * 16;
        {
            int cc = tid >> 4, n4 = (tid & 15) * 4;
            *(float4*)&Xi[cc][n4] =
                *(const float4*)&xb[(size_t)(c0 + cc) * NPT + n0 + n4];
        }
        {
            int oo = tid >> 2, c4 = (tid & 3) * 4;
            int o = o0 + oo;
            float4 w1 = *(const float4*)&cw[(size_t)o * 384 + c0 + c4];
            float4 w2 = *(const float4*)&cw[(size_t)o * 384 + C_ + c0 + c4];
            Wd[c4 + 0][oo] = w1.x - w2.x; Wd[c4 + 1][oo] = w1.y - w2.y;
            Wd[c4 + 2][oo] = w1.z - w2.z; Wd[c4 + 3][oo] = w1.w - w2.w;
        }
        __syncthreads();
#pragma unroll
        for (int cc = 0; cc < 16; ++cc) {
            float4 av = *(const float4*)&Xi[cc][ty * 4];
            float4 bv = *(const float4*)&Wd[cc][tx * 4];
            float a_[4] = {av.x, av.y, av.z, av.w};
            float b_[4] = {bv.x, bv.y, bv.z, bv.w};
#pragma unroll
            for (int u = 0; u < 4; ++u)
#pragma unroll
                for (int v = 0; v < 4; ++v)
                    zA[u][v] = fmaf(a_[u], b_[v], zA[u][v]);
        }
        __syncthreads();
    }

    const float inv_s = 0.9999950000374997f;  // 1/sqrt(1+1e-5)
    float gs[4], bts[4], cbs[4];
#pragma unroll
    for (int v = 0; v < 4; ++v) {
        int o = o0 + tx * 4 + v;
        gs[v]  = gam[o] * inv_s;
        bts[v] = bet[o];
        cbs[v] = cb[o];
    }

    float best[4][4];
#pragma unroll
    for (int u = 0; u < 4; ++u)
#pragma unroll
        for (int v = 0; v < 4; ++v) best[u][v] = -1e30f;

    int obB = o0 - bcol0;
    for (int k = 0; k < KNN; ++k) {
#pragma unroll
        for (int u = 0; u < 4; ++u) {
            int j = jidx[(ty * 4 + u) * KNN + k];
            float bvv[4];
            if (!readBf16) {
                float4 g = *(const float4*)
                    ((const float*)Bq + (size_t)j * ldB + obB + tx * 4);
                bvv[0] = g.x; bvv[1] = g.y; bvv[2] = g.z; bvv[3] = g.w;
            } else {
                ushort4 g = *(const ushort4*)
                    ((const unsigned short*)Bq + (size_t)j * ldB + obB + tx * 4);
                bvv[0] = u2f(g.x); bvv[1] = u2f(g.y);
                bvv[2] = u2f(g.z); bvv[3] = u2f(g.w);
            }
#pragma unroll
            for (int v = 0; v < 4; ++v) {
                float z = zA[u][v] + bvv[v] + cbs[v];
                float y = fmaf(z, gs[v], bts[v]);
                float ge = 0.5f * y * (1.0f + erff(y * 0.70710678118654752f));
                best[u][v] = fmaxf(best[u][v], ge);
            }
        }
    }

#pragma unroll
    for (int v = 0; v < 4; ++v) {
        int o = o0 + tx * 4 + v;
        float4 pk = {best[0][v], best[1][v], best[2][v], best[3][v]};
        *(float4*)(out + ((size_t)(b * CO_ + o)) * NPT + n0 + ty * 4) = pk;
    }
}

// ---------------------------------------------------------------------------
// K6: generate edge plane1 (center indices) last.
// ---------------------------------------------------------------------------
__global__ __launch_bounds__(256) void k_center(float* __restrict__ e1)
{
    int p = blockIdx.x * 256 + threadIdx.x;
    if (p >= NROWS * KNN) return;
    e1[p] = (float)((p / KNN) % NPT);
}

// ---------------------------------------------------------------------------
extern "C" void kernel_launch(void* const* d_in, const int* in_sizes, int n_in,
                              void* d_out, int out_size, void* d_ws, size_t ws_size,
                              hipStream_t stream)
{
    const float* x   = (const float*)d_in[0];
    const float* cw  = (const float*)d_in[1];
    const float* cb  = (const float*)d_in[2];
    const float* gam = (const float*)d_in[3];
    const float* bet = (const float*)d_in[4];

    // d_out: FLOAT32. out0 = floats [0, 4,816,896); e0 = [4,816,896,
    // 4,929,792); e1 = [4,929,792, 5,042,688).
    // Scratch liveness (all dead before their region's output write):
    //   head: invn64/sqd/invn32/cand  (bytes [0, 1,856,512))
    //   xT:   floats [2,408,448, 4,816,896)  — dead after k_refine
    float* ou   = (float*)d_out;
    float* out0 = ou;
    double* invn64 = (double*)d_out;
    double* sqd    = (double*)((char*)d_out + 100352);
    float*  invn32 = (float*)((char*)d_out + 200704);
    unsigned short* cand =
        (unsigned short*)((char*)d_out + 250880);          // 1,605,632 B
    float* xT = ou + 2408448;                              // 9.63 MB
    float* e0 = ou + 4816896;
    float* e1 = ou + 4929792;

    k_norm   <<<NROWS / 256, 256, 0, stream>>>(x, invn32, invn64, sqd);
    k_xpose  <<<B_ * 6 * 98, 256, 0, stream>>>(x, xT);
    k_screen3<<<B_ * 98 * 4, 128, 0, stream>>>(x, invn32, cand);
    k_refine <<<NROWS / 4, 256, 0, stream>>>(xT, invn64, sqd, cand, e0);

    // Batches 3,2,1: full B (3136x384 fp32 = 4.8 MB) in Q0 (free until b0).
    for (int b = 3; b >= 1; --b) {
        k_gemmB<<<49 * 6, 256, 0, stream>>>(x, cw, (void*)ou, b, 0, 384, 0);
        k_outA <<<49 * 6, 256, 0, stream>>>(x, cw, e0, cb, gam, bet, out0,
                                            (const void*)ou, b, 0, 0, 384, 0);
    }
    // Batch 0 in 3 bf16 col-chunks; B buffers in provably-dead space:
    //  1: cols [192,384) B bf16 @ Q0 bytes [0,1,204,224) out->[2,408,448,4,816,896)
    //  2: cols [ 64,192) B bf16 @ Q0 bytes [0,  802,816) out->[  802,816,2,408,448)
    //  3: cols [  0, 64) B bf16 @ e1      (401,408 B)    out->[        0,  802,816)
    k_gemmB<<<49 * 3, 256, 0, stream>>>(x, cw, (void*)ou, 0, 192, 192, 1);
    k_outA <<<49 * 3, 256, 0, stream>>>(x, cw, e0, cb, gam, bet, out0,
                                        (const void*)ou, 0, 192, 192, 192, 1);
    k_gemmB<<<49 * 2, 256, 0, stream>>>(x, cw, (void*)ou, 0, 64, 128, 1);
    k_outA <<<49 * 2, 256, 0, stream>>>(x, cw, e0, cb, gam, bet, out0,
                                        (const void*)ou, 0, 64, 64, 128, 1);
    k_gemmB<<<49 * 1, 256, 0, stream>>>(x, cw, (void*)e1, 0, 0, 64, 1);
    k_outA <<<49 * 1, 256, 0, stream>>>(x, cw, e0, cb, gam, bet, out0,
                                        (const void*)e1, 0, 0, 0, 64, 1);
    // Generate e1 (center plane) last.
    k_center<<<(NROWS * KNN + 255) / 256, 256, 0, stream>>>(e1);
}